// Round 1
// baseline (671.807 us; speedup 1.0000x reference)
//
#include <hip/hip_runtime.h>
#include <hip/hip_bf16.h>

#define N_NODES 12288
#define KNBR 32
#define D 128

using short8 = __attribute__((ext_vector_type(8))) short;
using f32x4  = __attribute__((ext_vector_type(4))) float;

static __device__ __forceinline__ unsigned short f32_to_bf16(float f) {
    unsigned int u = __float_as_uint(f);
    unsigned int r = (u + 0x7FFFu + ((u >> 16) & 1u)) >> 16;   // RNE
    return (unsigned short)r;
}

// ---------------------------------------------------------------------------
// K1: G = raw_features @ W_lin^T   (12288x128 @ 128x128), G stored as bf16.
// One wave (64 threads) per 16-row strip of G. 8 column tiles x 4 k-steps of
// mfma_f32_16x16x32_bf16.
//   A frag: lane holds A[m = lane&15][k = (lane>>4)*8 + j], j=0..7
//   B frag: lane holds B[k = (lane>>4)*8 + j][n = lane&15]  (= W[n][k], contig)
//   C/D:    col = lane&15, row = (lane>>4)*4 + reg
// ---------------------------------------------------------------------------
__global__ __launch_bounds__(64) void k1_gemm(const float* __restrict__ F,
                                              const float* __restrict__ W,
                                              unsigned short* __restrict__ G) {
    const int lane = threadIdx.x;
    const int l16  = lane & 15;
    const int quad = lane >> 4;
    const int m0   = blockIdx.x * 16;

    // A fragments for all 4 k-steps (each lane: 8 consecutive floats of its F row)
    short8 afrag[4];
    const float* Fr = F + (size_t)(m0 + l16) * D + quad * 8;
#pragma unroll
    for (int ks = 0; ks < 4; ++ks) {
        const float* p = Fr + ks * 32;
        short8 t;
#pragma unroll
        for (int j = 0; j < 8; ++j) t[j] = (short)f32_to_bf16(p[j]);
        afrag[ks] = t;
    }

    f32x4 acc[8];
#pragma unroll
    for (int jt = 0; jt < 8; ++jt) acc[jt] = (f32x4){0.f, 0.f, 0.f, 0.f};

#pragma unroll
    for (int jt = 0; jt < 8; ++jt) {
        const float* Wr = W + (size_t)(jt * 16 + l16) * D + quad * 8;
#pragma unroll
        for (int ks = 0; ks < 4; ++ks) {
            const float* p = Wr + ks * 32;
            short8 bfrag;
#pragma unroll
            for (int j = 0; j < 8; ++j) bfrag[j] = (short)f32_to_bf16(p[j]);
            acc[jt] = __builtin_amdgcn_mfma_f32_16x16x32_bf16(afrag[ks], bfrag, acc[jt], 0, 0, 0);
        }
    }

    // Store bf16 G
#pragma unroll
    for (int jt = 0; jt < 8; ++jt) {
#pragma unroll
        for (int r = 0; r < 4; ++r) {
            int row = m0 + quad * 4 + r;
            int col = jt * 16 + l16;
            G[(size_t)row * D + col] = f32_to_bf16(acc[jt][r]);
        }
    }
}

// ---------------------------------------------------------------------------
// K2: out[b][:] = relu( b_lin + sum_k w[b][k] * G[neighbors[b][k]][:] )
//     w[b][k] = (nbr==node) ? 0 : reweighted[node*N + nbr]
// One wave per node; lanes 0..31 gather neighbor ids + weights, broadcast via
// __shfl; each lane accumulates 2 output columns (coalesced dword G reads).
// ---------------------------------------------------------------------------
__global__ __launch_bounds__(256) void k2_agg(const int* __restrict__ nodes,
                                              const int* __restrict__ neighbors,
                                              const float* __restrict__ RW,
                                              const unsigned short* __restrict__ G,
                                              const float* __restrict__ b_lin,
                                              float* __restrict__ out) {
    const int wv   = threadIdx.x >> 6;
    const int lane = threadIdx.x & 63;
    const int b    = blockIdx.x * 4 + wv;

    const int node = nodes[b];

    int   nk = 0;
    float wk = 0.f;
    if (lane < KNBR) {
        nk = neighbors[b * KNBR + lane];
        wk = (nk == node) ? 0.f : RW[(size_t)node * N_NODES + nk];
    }

    float acc0 = b_lin[2 * lane];
    float acc1 = b_lin[2 * lane + 1];

#pragma unroll
    for (int k = 0; k < KNBR; ++k) {
        int   nn = __shfl(nk, k);
        float w  = __shfl(wk, k);
        unsigned int g = *(const unsigned int*)(G + (size_t)nn * D + 2 * lane);
        float g0 = __uint_as_float(g << 16);
        float g1 = __uint_as_float(g & 0xFFFF0000u);
        acc0 = fmaf(w, g0, acc0);
        acc1 = fmaf(w, g1, acc1);
    }

    float2 res;
    res.x = fmaxf(acc0, 0.f);
    res.y = fmaxf(acc1, 0.f);
    *(float2*)(out + (size_t)b * D + 2 * lane) = res;
}

extern "C" void kernel_launch(void* const* d_in, const int* in_sizes, int n_in,
                              void* d_out, int out_size, void* d_ws, size_t ws_size,
                              hipStream_t stream) {
    const int*   nodes     = (const int*)d_in[0];
    const int*   neighbors = (const int*)d_in[1];
    const float* F         = (const float*)d_in[2];   // raw_features (N, 128)
    const float* RW        = (const float*)d_in[3];   // reweighted   (N, N)
    const float* W         = (const float*)d_in[4];   // W_lin        (128, 128)
    const float* bl        = (const float*)d_in[5];   // b_lin        (128,)
    float*       out       = (float*)d_out;

    unsigned short* G = (unsigned short*)d_ws;        // (N, 128) bf16 = 3.15 MB

    k1_gemm<<<N_NODES / 16, 64, 0, stream>>>(F, W, G);
    k2_agg<<<N_NODES / 4, 256, 0, stream>>>(nodes, neighbors, RW, G, bl, out);
}

// Round 2
// 669.331 us; speedup vs baseline: 1.0037x; 1.0037x over previous
//
#include <hip/hip_runtime.h>
#include <hip/hip_bf16.h>

#define N_NODES 12288
#define KNBR 32
#define D 128

using short8 = __attribute__((ext_vector_type(8))) short;
using f32x4  = __attribute__((ext_vector_type(4))) float;

static __device__ __forceinline__ unsigned short f32_to_bf16(float f) {
    unsigned int u = __float_as_uint(f);
    unsigned int r = (u + 0x7FFFu + ((u >> 16) & 1u)) >> 16;   // RNE
    return (unsigned short)r;
}

// ---------------------------------------------------------------------------
// K1: G = raw_features @ W_lin^T   (12288x128 @ 128x128), G stored as bf16.
// One wave (64 threads) per 16-row strip of G. 8 column tiles x 4 k-steps of
// mfma_f32_16x16x32_bf16.  (unchanged from R1 — verified absmax 0.25)
// ---------------------------------------------------------------------------
__global__ __launch_bounds__(64) void k1_gemm(const float* __restrict__ F,
                                              const float* __restrict__ W,
                                              unsigned short* __restrict__ G) {
    const int lane = threadIdx.x;
    const int l16  = lane & 15;
    const int quad = lane >> 4;
    const int m0   = blockIdx.x * 16;

    short8 afrag[4];
    const float* Fr = F + (size_t)(m0 + l16) * D + quad * 8;
#pragma unroll
    for (int ks = 0; ks < 4; ++ks) {
        const float* p = Fr + ks * 32;
        short8 t;
#pragma unroll
        for (int j = 0; j < 8; ++j) t[j] = (short)f32_to_bf16(p[j]);
        afrag[ks] = t;
    }

    f32x4 acc[8];
#pragma unroll
    for (int jt = 0; jt < 8; ++jt) acc[jt] = (f32x4){0.f, 0.f, 0.f, 0.f};

#pragma unroll
    for (int jt = 0; jt < 8; ++jt) {
        const float* Wr = W + (size_t)(jt * 16 + l16) * D + quad * 8;
#pragma unroll
        for (int ks = 0; ks < 4; ++ks) {
            const float* p = Wr + ks * 32;
            short8 bfrag;
#pragma unroll
            for (int j = 0; j < 8; ++j) bfrag[j] = (short)f32_to_bf16(p[j]);
            acc[jt] = __builtin_amdgcn_mfma_f32_16x16x32_bf16(afrag[ks], bfrag, acc[jt], 0, 0, 0);
        }
    }

#pragma unroll
    for (int jt = 0; jt < 8; ++jt) {
#pragma unroll
        for (int r = 0; r < 4; ++r) {
            int row = m0 + quad * 4 + r;
            int col = jt * 16 + l16;
            G[(size_t)row * D + col] = f32_to_bf16(acc[jt][r]);
        }
    }
}

// ---------------------------------------------------------------------------
// K2 (restructured): one wave per node; 4 neighbors per iteration.
//   lane = 16-lane group `grp` (0..3) x column-slice `l16` (cols l16*8..+7).
//   Group g loads neighbor (kb+g)'s G row as dwordx4 (8 bf16 = 16 B/lane,
//   16 lanes = full 256 B row, coalesced). 8 iterations instead of 32.
//   Final: shfl_xor(16), shfl_xor(32) butterfly sums the 4 group partials;
//   lanes with grp==0 add bias, relu, and store 2x float4.
// ---------------------------------------------------------------------------
__global__ __launch_bounds__(256) void k2_agg(const int* __restrict__ nodes,
                                              const int* __restrict__ neighbors,
                                              const float* __restrict__ RW,
                                              const unsigned short* __restrict__ G,
                                              const float* __restrict__ b_lin,
                                              float* __restrict__ out) {
    const int wv   = threadIdx.x >> 6;
    const int lane = threadIdx.x & 63;
    const int b    = blockIdx.x * 4 + wv;
    const int grp  = lane >> 4;    // 0..3: which neighbor of the 4-batch
    const int l16  = lane & 15;    // column slice: cols l16*8 .. l16*8+7

    const int node = nodes[b];

    // lanes 0..31: neighbor id + masked weight for k = lane
    int   nk = 0;
    float wk = 0.f;
    if (lane < KNBR) {
        nk = neighbors[b * KNBR + lane];
        wk = (nk == node) ? 0.f : RW[(size_t)node * N_NODES + nk];
    }

    float acc[8];
#pragma unroll
    for (int j = 0; j < 8; ++j) acc[j] = 0.f;

#pragma unroll
    for (int kb = 0; kb < KNBR; kb += 4) {
        int   nn = __shfl(nk, kb + grp);
        float w  = __shfl(wk, kb + grp);
        const uint4 g = *(const uint4*)(G + (size_t)nn * D + l16 * 8);
        acc[0] = fmaf(w, __uint_as_float(g.x << 16),         acc[0]);
        acc[1] = fmaf(w, __uint_as_float(g.x & 0xFFFF0000u), acc[1]);
        acc[2] = fmaf(w, __uint_as_float(g.y << 16),         acc[2]);
        acc[3] = fmaf(w, __uint_as_float(g.y & 0xFFFF0000u), acc[3]);
        acc[4] = fmaf(w, __uint_as_float(g.z << 16),         acc[4]);
        acc[5] = fmaf(w, __uint_as_float(g.z & 0xFFFF0000u), acc[5]);
        acc[6] = fmaf(w, __uint_as_float(g.w << 16),         acc[6]);
        acc[7] = fmaf(w, __uint_as_float(g.w & 0xFFFF0000u), acc[7]);
    }

    // combine the 4 group partials (lanes differing in bits 4,5)
#pragma unroll
    for (int j = 0; j < 8; ++j) {
        acc[j] += __shfl_xor(acc[j], 16);
        acc[j] += __shfl_xor(acc[j], 32);
    }

    if (grp == 0) {
        const float4 bia0 = *(const float4*)(b_lin + l16 * 8);
        const float4 bia1 = *(const float4*)(b_lin + l16 * 8 + 4);
        float4 r0, r1;
        r0.x = fmaxf(acc[0] + bia0.x, 0.f);
        r0.y = fmaxf(acc[1] + bia0.y, 0.f);
        r0.z = fmaxf(acc[2] + bia0.z, 0.f);
        r0.w = fmaxf(acc[3] + bia0.w, 0.f);
        r1.x = fmaxf(acc[4] + bia1.x, 0.f);
        r1.y = fmaxf(acc[5] + bia1.y, 0.f);
        r1.z = fmaxf(acc[6] + bia1.z, 0.f);
        r1.w = fmaxf(acc[7] + bia1.w, 0.f);
        float* o = out + (size_t)b * D + l16 * 8;
        *(float4*)o       = r0;
        *(float4*)(o + 4) = r1;
    }
}

extern "C" void kernel_launch(void* const* d_in, const int* in_sizes, int n_in,
                              void* d_out, int out_size, void* d_ws, size_t ws_size,
                              hipStream_t stream) {
    const int*   nodes     = (const int*)d_in[0];
    const int*   neighbors = (const int*)d_in[1];
    const float* F         = (const float*)d_in[2];   // raw_features (N, 128)
    const float* RW        = (const float*)d_in[3];   // reweighted   (N, N)
    const float* W         = (const float*)d_in[4];   // W_lin        (128, 128)
    const float* bl        = (const float*)d_in[5];   // b_lin        (128,)
    float*       out       = (float*)d_out;

    unsigned short* G = (unsigned short*)d_ws;        // (N, 128) bf16 = 3.15 MB

    k1_gemm<<<N_NODES / 16, 64, 0, stream>>>(F, W, G);
    k2_agg<<<N_NODES / 4, 256, 0, stream>>>(nodes, neighbors, RW, G, bl, out);
}